// Round 1
// baseline (806.941 us; speedup 1.0000x reference)
//
#include <hip/hip_runtime.h>
#include <math.h>

#define N_NODES 100000
#define N_EDGES 1600000
#define HID 64
#define OUTC 40

#define SCAN_BLOCK 1024
#define SCAN_NBLK ((N_NODES + SCAN_BLOCK - 1) / SCAN_BLOCK)   // 98

// ---------------- CSR build ----------------

__global__ __launch_bounds__(256) void k_deg(const int* __restrict__ src,
                                             const int* __restrict__ dst,
                                             int* __restrict__ deg_src,
                                             int* __restrict__ deg_dst) {
    int e = blockIdx.x * 256 + threadIdx.x;
    if (e < N_EDGES) {
        atomicAdd(&deg_src[src[e]], 1);
        atomicAdd(&deg_dst[dst[e]], 1);
    }
}

__global__ __launch_bounds__(256) void k_maxdeg(const int* __restrict__ deg_src,
                                                int* __restrict__ maxdeg) {
    int i = blockIdx.x * 256 + threadIdx.x;
    int v = (i < N_NODES) ? deg_src[i] : 0;
    for (int off = 32; off; off >>= 1) v = max(v, __shfl_down(v, off));
    __shared__ int smax[4];
    int lane = threadIdx.x & 63, w = threadIdx.x >> 6;
    if (lane == 0) smax[w] = v;
    __syncthreads();
    if (threadIdx.x == 0) {
        int m = smax[0];
        for (int j = 1; j < 4; j++) m = max(m, smax[j]);
        atomicMax(maxdeg, m);
    }
}

// inclusive scan of deg_dst per 1024-chunk -> rowptr[i+1]; block totals out
__global__ __launch_bounds__(SCAN_BLOCK) void k_scan1(const int* __restrict__ deg_dst,
                                                      int* __restrict__ rowptr,
                                                      int* __restrict__ blocksum) {
    __shared__ int buf[2][SCAN_BLOCK];
    int t = threadIdx.x;
    int i = blockIdx.x * SCAN_BLOCK + t;
    int v = (i < N_NODES) ? deg_dst[i] : 0;
    int cur = 0;
    buf[0][t] = v;
    __syncthreads();
    for (int off = 1; off < SCAN_BLOCK; off <<= 1) {
        int nv = buf[cur][t];
        if (t >= off) nv += buf[cur][t - off];
        buf[1 - cur][t] = nv;
        cur = 1 - cur;
        __syncthreads();
    }
    int incl = buf[cur][t];
    if (i < N_NODES) rowptr[i + 1] = incl;
    if (t == SCAN_BLOCK - 1) blocksum[blockIdx.x] = incl;
}

// add chunk offsets; set rowptr[0]=0
__global__ __launch_bounds__(SCAN_BLOCK) void k_scan2(int* __restrict__ rowptr,
                                                      const int* __restrict__ blocksum) {
    __shared__ int offs[SCAN_NBLK];
    if (threadIdx.x == 0) {
        int run = 0;
        for (int b = 0; b < SCAN_NBLK; b++) { offs[b] = run; run += blocksum[b]; }
        rowptr[0] = 0;
    }
    __syncthreads();
    for (int i = threadIdx.x; i < N_NODES; i += SCAN_BLOCK)
        rowptr[i + 1] += offs[i / SCAN_BLOCK];
}

__global__ __launch_bounds__(256) void k_fill(const int* __restrict__ src,
                                              const int* __restrict__ dst,
                                              const int* __restrict__ rowptr,
                                              int* __restrict__ cnt,
                                              int* __restrict__ csr_src) {
    int e = blockIdx.x * 256 + threadIdx.x;
    if (e < N_EDGES) {
        int d = dst[e];
        int p = rowptr[d] + atomicAdd(&cnt[d], 1);
        csr_src[p] = src[e];
    }
}

// ---------------- SpMM: Tx[i] = norm_loop[i]*h[i] - scale * sum_{e:dst=i} h[src_e] ----------
// one wave per node, lane = channel
__global__ __launch_bounds__(256) void k_spmm(const float* __restrict__ h,
                                              float* __restrict__ out,
                                              const int* __restrict__ rowptr,
                                              const int* __restrict__ csr_src,
                                              const int* __restrict__ deg_src,
                                              const int* __restrict__ maxdeg) {
    int wave = threadIdx.x >> 6;
    int lane = threadIdx.x & 63;
    int i = blockIdx.x * 4 + wave;   // grid is exactly N/4
    float scale = 1.0f / (float)(*maxdeg);
    float hv = h[i * 64 + lane];
    int e0 = rowptr[i], e1 = rowptr[i + 1];
    float acc0 = 0.f, acc1 = 0.f;
    for (int base = e0; base < e1; base += 64) {
        int n = min(64, e1 - base);
        int idx = (base + lane < e1) ? csr_src[base + lane] : 0;
        int j = 0;
        for (; j + 4 <= n; j += 4) {
            int s0 = __shfl(idx, j);
            int s1 = __shfl(idx, j + 1);
            int s2 = __shfl(idx, j + 2);
            int s3 = __shfl(idx, j + 3);
            float a0 = h[s0 * 64 + lane];
            float a1 = h[s1 * 64 + lane];
            float a2 = h[s2 * 64 + lane];
            float a3 = h[s3 * 64 + lane];
            acc0 += a0 + a2;
            acc1 += a1 + a3;
        }
        for (; j < n; j++) {
            int s = __shfl(idx, j);
            acc0 += h[s * 64 + lane];
        }
    }
    float norm_loop = (float)deg_src[i] * scale - 1.0f;
    out[i * 64 + lane] = norm_loop * hv - scale * (acc0 + acc1);
}

// ---------------- layer: out = h@W0 + Tx@W1 + b (+relu), 64->64 ----------------
__global__ __launch_bounds__(256) void k_layer64(const float* __restrict__ h,
                                                 const float* __restrict__ tx,
                                                 const float* __restrict__ W0,
                                                 const float* __restrict__ W1,
                                                 const float* __restrict__ b,
                                                 float* __restrict__ out) {
    __shared__ float sw0[64 * 64], sw1[64 * 64];
    __shared__ float sh[4 * 64], st[4 * 64];
    int t = threadIdx.x;
    for (int k = t; k < 64 * 64; k += 256) { sw0[k] = W0[k]; sw1[k] = W1[k]; }
    int r = t >> 6, c = t & 63;
    int i = blockIdx.x * 4 + r;    // grid exactly N/4
    sh[t] = h[i * 64 + c];
    st[t] = tx[i * 64 + c];
    __syncthreads();
    float acc = b[c];
    #pragma unroll
    for (int k = 0; k < 64; k++) {
        acc += sh[r * 64 + k] * sw0[k * 64 + c];
        acc += st[r * 64 + k] * sw1[k * 64 + c];
    }
    out[i * 64 + c] = fmaxf(acc, 0.f);
}

// ---------------- final layer: 64->40 + log_softmax ----------------
__global__ __launch_bounds__(256) void k_layer40(const float* __restrict__ h,
                                                 const float* __restrict__ tx,
                                                 const float* __restrict__ W0,
                                                 const float* __restrict__ W1,
                                                 const float* __restrict__ b,
                                                 float* __restrict__ out) {
    __shared__ float sw0[64 * 40], sw1[64 * 40];
    __shared__ float sh[4 * 64], st[4 * 64];
    int t = threadIdx.x;
    for (int k = t; k < 64 * 40; k += 256) { sw0[k] = W0[k]; sw1[k] = W1[k]; }
    int r = t >> 6, c = t & 63;
    int i = blockIdx.x * 4 + r;    // grid exactly N/4
    sh[t] = h[i * 64 + c];
    st[t] = tx[i * 64 + c];
    __syncthreads();
    float v = 0.f;
    if (c < OUTC) {
        v = b[c];
        #pragma unroll
        for (int k = 0; k < 64; k++) {
            v += sh[r * 64 + k] * sw0[k * OUTC + c];
            v += st[r * 64 + k] * sw1[k * OUTC + c];
        }
    }
    float x = (c < OUTC) ? v : -INFINITY;
    float m = x;
    for (int off = 32; off; off >>= 1) m = fmaxf(m, __shfl_xor(m, off));
    float ex = (c < OUTC) ? __expf(v - m) : 0.f;
    float s = ex;
    for (int off = 32; off; off >>= 1) s += __shfl_xor(s, off);
    if (c < OUTC) out[i * OUTC + c] = v - m - __logf(s);
}

// ---------------- launch ----------------

extern "C" void kernel_launch(void* const* d_in, const int* in_sizes, int n_in,
                              void* d_out, int out_size, void* d_ws, size_t ws_size,
                              hipStream_t stream) {
    const float* x   = (const float*)d_in[0];
    const int* ei    = (const int*)d_in[1];
    const int* src   = ei;
    const int* dst   = ei + N_EDGES;
    const float* W0_0 = (const float*)d_in[2];
    const float* W1_0 = (const float*)d_in[3];
    const float* b_0  = (const float*)d_in[4];
    const float* W0_1 = (const float*)d_in[5];
    const float* W1_1 = (const float*)d_in[6];
    const float* b_1  = (const float*)d_in[7];
    const float* W0_2 = (const float*)d_in[8];
    const float* W1_2 = (const float*)d_in[9];
    const float* b_2  = (const float*)d_in[10];
    float* outp = (float*)d_out;

    // workspace layout (int elements)
    int* base = (int*)d_ws;
    int* deg_src = base;                         // N
    int* deg_dst = base + N_NODES;               // N
    int* cnt     = base + 2 * N_NODES;           // N
    int* maxdeg  = base + 3 * N_NODES;           // 1
    const size_t ZERO_INTS = 3 * (size_t)N_NODES + 1;
    int* rowptr   = base + 300064;               // N+1 -> pad to 100032
    int* blocksum = base + 300064 + 100032;      // 128
    int* csr_src  = base + 300064 + 100032 + 128; // E
    float* fbase  = (float*)(base + 300064 + 100032 + 128 + N_EDGES);
    float* hA = fbase;                            // N*64
    float* hB = fbase + (size_t)N_NODES * 64;     // N*64
    float* Tx = fbase + 2 * (size_t)N_NODES * 64; // N*64

    hipMemsetAsync(d_ws, 0, ZERO_INTS * sizeof(int), stream);

    k_deg<<<N_EDGES / 256, 256, 0, stream>>>(src, dst, deg_src, deg_dst);
    k_maxdeg<<<(N_NODES + 255) / 256, 256, 0, stream>>>(deg_src, maxdeg);
    k_scan1<<<SCAN_NBLK, SCAN_BLOCK, 0, stream>>>(deg_dst, rowptr, blocksum);
    k_scan2<<<1, SCAN_BLOCK, 0, stream>>>(rowptr, blocksum);
    k_fill<<<N_EDGES / 256, 256, 0, stream>>>(src, dst, rowptr, cnt, csr_src);

    const int GN = N_NODES / 4;   // 25000, exact

    // layer 0: x -> hA
    k_spmm<<<GN, 256, 0, stream>>>(x, Tx, rowptr, csr_src, deg_src, maxdeg);
    k_layer64<<<GN, 256, 0, stream>>>(x, Tx, W0_0, W1_0, b_0, hA);
    // layer 1: hA -> hB
    k_spmm<<<GN, 256, 0, stream>>>(hA, Tx, rowptr, csr_src, deg_src, maxdeg);
    k_layer64<<<GN, 256, 0, stream>>>(hA, Tx, W0_1, W1_1, b_1, hB);
    // layer 2: hB -> out (log_softmax)
    k_spmm<<<GN, 256, 0, stream>>>(hB, Tx, rowptr, csr_src, deg_src, maxdeg);
    k_layer40<<<GN, 256, 0, stream>>>(hB, Tx, W0_2, W1_2, b_2, outp);
}